// Round 10
// baseline (224.462 us; speedup 1.0000x reference)
//
#include <hip/hip_runtime.h>
#include <cstdint>
#include <cstddef>

static constexpr int kT  = 2048;
static constexpr int kD  = 512;
static constexpr int kB  = 2;
static constexpr int kN  = kB * kT;   // 4096 rows
static constexpr int kTP = kT + 2;    // padded rows per batch (2050)

using short8 = __attribute__((ext_vector_type(8))) short;
using f32x4  = __attribute__((ext_vector_type(4))) float;
typedef unsigned short ushort;

__device__ inline ushort f2bf(float f) {
  uint32_t u = __builtin_bit_cast(uint32_t, f);
  uint32_t r = (u + 0x7FFFu + ((u >> 16) & 1u)) >> 16;
  return (ushort)r;
}

#define GLOAD_LDS16(g, l)                                         \
  __builtin_amdgcn_global_load_lds(                               \
      (const __attribute__((address_space(1))) void*)(g),         \
      (__attribute__((address_space(3))) void*)(l), 16, 0, 0)

struct __align__(16) SmemGemm {
  ushort As[2][64 * 128];
  ushort Bs[2][64 * 128];
};                                        // 64 KB

// ---------------------------------------------------------------- fused prep
// xbp: per-batch zero-padded bf16 x (row b*2050: zero, rows 1..2048: x,
// row 2049: zero). Plus weight casts, wct transpose, bvpart partials.
__global__ __launch_bounds__(256) void prep_kernel(
    const float* __restrict__ x,   const float* __restrict__ ipw,
    const float* __restrict__ opw, const float* __restrict__ w1,
    const float* __restrict__ w2,  const float* __restrict__ cw,
    const float* __restrict__ cb,
    ushort* __restrict__ xbp,  ushort* __restrict__ ipwb,
    ushort* __restrict__ opwb, ushort* __restrict__ w1b,
    ushort* __restrict__ w2b,  ushort* __restrict__ wct,
    float* __restrict__ bvpart)
{
  constexpr int C0 = kB * kTP * 64;     // xbp units (8 bf16 each) = 262400
  constexpr int C1 = C0 + 196608;       // ipw (float4 units)
  constexpr int C2 = C1 + 65536;        // opw
  constexpr int C3 = C2 + 131072;       // w1
  constexpr int C4 = C3 + 131072;       // w2
  constexpr int C5 = C4 + 786432;       // wct (ti,c) ushort units
  constexpr int C6 = C5 + 4096;         // bvpart (o,seg)

  auto cast4 = [](const float* in, ushort* out, int u) {
    float4 v = *reinterpret_cast<const float4*>(&in[(size_t)u * 4]);
    ushort o[4] = {f2bf(v.x), f2bf(v.y), f2bf(v.z), f2bf(v.w)};
    *reinterpret_cast<uint2*>(&out[(size_t)u * 4]) =
        *reinterpret_cast<uint2*>(o);
  };

  for (int u = blockIdx.x * 256 + threadIdx.x; u < C6; u += gridDim.x * 256) {
    if (u < C0) {
      int r = u >> 6, c8 = u & 63;
      int b = r / kTP, rr = r - b * kTP;
      ushort ob[8] = {0, 0, 0, 0, 0, 0, 0, 0};
      if (rr >= 1 && rr <= kT) {
        const float* src = &x[(size_t)(b * kT + rr - 1) * kD + c8 * 8];
        float4 v0 = *reinterpret_cast<const float4*>(src);
        float4 v1 = *reinterpret_cast<const float4*>(src + 4);
        ob[0] = f2bf(v0.x); ob[1] = f2bf(v0.y); ob[2] = f2bf(v0.z);
        ob[3] = f2bf(v0.w); ob[4] = f2bf(v1.x); ob[5] = f2bf(v1.y);
        ob[6] = f2bf(v1.z); ob[7] = f2bf(v1.w);
      }
      *reinterpret_cast<uint4*>(&xbp[(size_t)u * 8]) =
          *reinterpret_cast<uint4*>(ob);
    } else if (u < C1) {
      cast4(ipw, ipwb, u - C0);
    } else if (u < C2) {
      cast4(opw, opwb, u - C1);
    } else if (u < C3) {
      cast4(w1, w1b, u - C2);
    } else if (u < C4) {
      cast4(w2, w2b, u - C3);
    } else if (u < C5) {
      int t = u - C4;
      int ti = t >> 9, c = t & 511;        // ti = tap*512 + i
      int tap = ti >> 9, i = ti & 511;
      wct[(size_t)ti * 512 + c] = f2bf(cw[((size_t)c * 512 + i) * 3 + tap]);
    } else {
      int t = u - C5;
      int o = t >> 3, seg = t & 7;
      float s = 0.f;
      const float* wr = &ipw[(size_t)(1024 + o) * kD + seg * 64];
      const float* cr = &cb[seg * 64];
#pragma unroll 8
      for (int c = 0; c < 64; ++c) s = fmaf(wr[c], cr[c], s);
      bvpart[t] = s;
    }
  }
}

// ---------------------------------------------------------------- GEMM tile (device)
// One 64x64 tile: C = Atile[64,K](lda) @ W[Nn,K]^T + bias. BK=128, 4 waves,
// 2-buffer LDS, 1-ahead prefetch, counted vmcnt, XOR swizzle.
template <typename OutT, int RELU>
__device__ void gemm_tile(SmemGemm& S,
    const ushort* __restrict__ Atile, int lda,
    const ushort* __restrict__ W,
    const float* __restrict__ bias, OutT* __restrict__ C,
    int Nn, int K, int m0, int n0)
{
  const int tid = threadIdx.x;
  const int lane = tid & 63, w = tid >> 6;
  const int wr = w >> 1, wc = w & 1;
  const int fr = lane & 15, g = lane >> 4;

  f32x4 acc[2][2];
#pragma unroll
  for (int i = 0; i < 2; ++i)
#pragma unroll
    for (int j = 0; j < 2; ++j) acc[i][j] = {0.f, 0.f, 0.f, 0.f};

  const ushort* gA[4];
  const ushort* gB[4];
#pragma unroll
  for (int i = 0; i < 4; ++i) {
    int u = i * 256 + tid;
    int row = u >> 4, c = (u & 15) ^ (row & 7);
    gA[i] = Atile + (size_t)row * lda + c * 8;
    gB[i] = W + (size_t)(n0 + row) * K + c * 8;
  }

  auto stage = [&](int buf, int k0) {
#pragma unroll
    for (int i = 0; i < 4; ++i)
      GLOAD_LDS16(gA[i] + k0, &S.As[buf][(i * 256 + w * 64) * 8]);
#pragma unroll
    for (int i = 0; i < 4; ++i)
      GLOAD_LDS16(gB[i] + k0, &S.Bs[buf][(i * 256 + w * 64) * 8]);
  };

  const int nt = K >> 7;
  stage(0, 0);
  for (int t = 0; t < nt; ++t) {
    const int buf = t & 1;
    if (t + 1 < nt) {
      stage(buf ^ 1, (t + 1) << 7);
      asm volatile("s_waitcnt vmcnt(8)" ::: "memory");
    } else {
      asm volatile("s_waitcnt vmcnt(0)" ::: "memory");
    }
    __builtin_amdgcn_s_barrier();
    __builtin_amdgcn_sched_barrier(0);

    short8 av[2][4], bv[2][4];
#pragma unroll
    for (int m = 0; m < 2; ++m)
#pragma unroll
      for (int kc = 0; kc < 4; ++kc) {
        int r = wr * 32 + m * 16 + fr;
        av[m][kc] = *reinterpret_cast<const short8*>(
            &S.As[buf][(r * 16 + ((kc * 4 + g) ^ (r & 7))) * 8]);
      }
#pragma unroll
    for (int n = 0; n < 2; ++n)
#pragma unroll
      for (int kc = 0; kc < 4; ++kc) {
        int r = wc * 32 + n * 16 + fr;
        bv[n][kc] = *reinterpret_cast<const short8*>(
            &S.Bs[buf][(r * 16 + ((kc * 4 + g) ^ (r & 7))) * 8]);
      }
#pragma unroll
    for (int m = 0; m < 2; ++m)
#pragma unroll
      for (int n = 0; n < 2; ++n)
#pragma unroll
        for (int kc = 0; kc < 4; ++kc)
          acc[m][n] = __builtin_amdgcn_mfma_f32_16x16x32_bf16(
              av[m][kc], bv[n][kc], acc[m][n], 0, 0, 0);

    __builtin_amdgcn_sched_barrier(0);
    __builtin_amdgcn_s_barrier();
  }

  float bb[2];
#pragma unroll
  for (int n = 0; n < 2; ++n)
    bb[n] = bias ? bias[n0 + wc * 32 + n * 16 + fr] : 0.f;
#pragma unroll
  for (int m = 0; m < 2; ++m) {
#pragma unroll
    for (int j = 0; j < 4; ++j) {
      int row = m0 + wr * 32 + m * 16 + g * 4 + j;
#pragma unroll
      for (int n = 0; n < 2; ++n) {
        int col = n0 + wc * 32 + n * 16 + fr;
        float v = acc[m][n][j] + bb[n];
        if (RELU) v = fmaxf(v, 0.f);
        if constexpr (sizeof(OutT) == 2)
          C[(size_t)row * Nn + col] = (OutT)f2bf(v);
        else
          C[(size_t)row * Nn + col] = (OutT)v;
      }
    }
  }
}

// ---------------------------------------------------------------- GEMM kernels
template <typename OutT, int RELU>
__global__ __launch_bounds__(256) void gemm_bf16(
    const ushort* __restrict__ A, const ushort* __restrict__ W,
    const float* __restrict__ bias, OutT* __restrict__ C, int Nn, int K)
{
  __shared__ SmemGemm S;
  const int m0 = blockIdx.x * 64;
  gemm_tile<OutT, RELU>(S, A + (size_t)m0 * K, K, W, bias, C, Nn, K,
                        m0, blockIdx.y * 64);
}

// Wv_eff = Wv @ Wc^T-form, plus bveff reduction.
__global__ __launch_bounds__(256) void wprep_kernel(
    const ushort* __restrict__ ipwb, const ushort* __restrict__ wct,
    ushort* __restrict__ wveff, const float* __restrict__ ipb,
    const float* __restrict__ bvpart, float* __restrict__ bveff)
{
  __shared__ SmemGemm S;
  const int bid = blockIdx.x;
  const int m0 = (bid / 24) * 64, n0 = (bid % 24) * 64;
  gemm_tile<ushort, 0>(S, ipwb + (size_t)(1024 + m0) * kD, kD, wct,
                       nullptr, wveff, 3 * kD, kD, m0, n0);
  if (bid < 2) {
    int o = bid * 256 + threadIdx.x;
    float s = ipb[1024 + o];
#pragma unroll
    for (int e = 0; e < 8; ++e) s += bvpart[o * 8 + e];
    bveff[o] = s;
  }
}

// q,k (xbp offset +1 row, K=512) and v (xbp strided-view im2col, K=1536).
__global__ __launch_bounds__(256) void qkv_kernel(
    const ushort* __restrict__ xbp,
    const ushort* __restrict__ ipwb, const float* __restrict__ ipb,
    const ushort* __restrict__ wveff, const float* __restrict__ bveff,
    ushort* __restrict__ qkb, ushort* __restrict__ vbb)
{
  __shared__ SmemGemm S;
  const int bid = blockIdx.x;
  if (bid < 1024) {
    const int m0 = (bid >> 4) * 64;
    const int bt = m0 >> 11, mi = m0 & (kT - 1);
    gemm_tile<ushort, 0>(S, xbp + (size_t)(bt * kTP + 1 + mi) * kD, kD,
                         ipwb, ipb, qkb, 1024, kD, m0, (bid & 15) * 64);
  } else {
    const int t = bid - 1024;
    const int m0 = (t >> 3) * 64;
    const int bt = m0 >> 11, mi = m0 & (kT - 1);
    // row r of the A-view = padded row bt*kTP + mi + r  (= x[m-1] base)
    gemm_tile<ushort, 0>(S, xbp + (size_t)(bt * kTP + mi) * kD, kD,
                         wveff, bveff, vbb, kD, 3 * kD, m0, (t & 7) * 64);
  }
}

// ---------------------------------------------------------------- GEMM + residual + LayerNorm
// BM=16, BN=512(all cols). C = A[16,KT] @ W[512,KT]^T + bias;
// y = LN(res + C)*G + Bt. Writes Out f32 (+OutB bf16 if BF16OUT).
template <int KT, int BF16OUT>
__global__ __launch_bounds__(256) void gemm_ln(
    const ushort* __restrict__ A, const ushort* __restrict__ W,
    const float* __restrict__ bias, const float* __restrict__ res,
    const float* __restrict__ G, const float* __restrict__ Bt,
    float* __restrict__ Out, ushort* __restrict__ OutB)
{
  constexpr int KTU = KT / 8;           // 16B units per A row
  constexpr int NCH = KT / 32;          // k-chunks
  __shared__ __align__(16) ushort As[16 * KT];       // 16/32 KB
  __shared__ __align__(16) ushort Bs[2][512 * 32];   // 2 x 32 KB
  const int tid = threadIdx.x;
  const int lane = tid & 63, w = tid >> 6;
  const int l15 = lane & 15, g = lane >> 4;
  const int m0 = blockIdx.x * 16;

  // stage A fully (XOR-swizzled source, linear LDS dest)
  constexpr int AISS = (16 * KTU) / 256;   // 4 or 8
  const ushort* gA[AISS];
#pragma unroll
  for (int i = 0; i < AISS; ++i) {
    int idx = i * 256 + tid;
    int row = idx / KTU, c = idx % KTU;
    int cs = (c & ~7) | ((c & 7) ^ (row & 7));
    gA[i] = A + (size_t)(m0 + row) * KT + cs * 8;
  }
  const ushort* gB[8];
#pragma unroll
  for (int i = 0; i < 8; ++i) {
    int idx = i * 256 + tid;
    int col = idx >> 2, uu = idx & 3;
    gB[i] = W + (size_t)col * KT + uu * 8;
  }

  auto stageB = [&](int buf, int k0) {
#pragma unroll
    for (int i = 0; i < 8; ++i)
      GLOAD_LDS16(gB[i] + k0, &Bs[buf][(i * 256 + w * 64) * 8]);
  };
#pragma unroll
  for (int i = 0; i < AISS; ++i)
    GLOAD_LDS16(gA[i], &As[(i * 256 + w * 64) * 8]);
  stageB(0, 0);

  f32x4 acc[8];
#pragma unroll
  for (int f = 0; f < 8; ++f) acc[f] = {0.f, 0.f, 0.f, 0.f};

  for (int t = 0; t < NCH; ++t) {
    const int buf = t & 1;
    if (t + 1 < NCH) {
      stageB(buf ^ 1, (t + 1) * 32);
      asm volatile("s_waitcnt vmcnt(8)" ::: "memory");
    } else {
      asm volatile("s_waitcnt vmcnt(0)" ::: "memory");
    }
    __builtin_amdgcn_s_barrier();
    __builtin_amdgcn_sched_barrier(0);

    short8 a = *reinterpret_cast<const short8*>(
        &As[(l15 * KTU + ((t * 4 + g) ^ (l15 & 7))) * 8]);
#pragma unroll
    for (int f = 0; f < 8; ++f) {
      int col = w * 128 + f * 16 + l15;
      short8 bv = *reinterpret_cast<const short8*>(&Bs[buf][(col * 4 + g) * 8]);
      acc[f] = __builtin_amdgcn_mfma_f32_16x16x32_bf16(a, bv, acc[f], 0, 0, 0);
    }
    __builtin_amdgcn_sched_barrier(0);
    __builtin_amdgcn_s_barrier();
  }

  // r = C + bias + res  (C-layout: row = g*4+j, col = w*128 + f*16 + l15)
  float bb[8], gg[8], tt[8];
#pragma unroll
  for (int f = 0; f < 8; ++f) {
    int col = w * 128 + f * 16 + l15;
    bb[f] = bias[col]; gg[f] = G[col]; tt[f] = Bt[col];
  }
#pragma unroll
  for (int f = 0; f < 8; ++f) {
    int col = w * 128 + f * 16 + l15;
#pragma unroll
    for (int j = 0; j < 4; ++j)
      acc[f][j] += bb[f] + res[(size_t)(m0 + g * 4 + j) * kD + col];
  }
  // per-row stats: reduce over f then over l15 lanes
  float sum[4], sq[4];
#pragma unroll
  for (int j = 0; j < 4; ++j) {
    float s = 0.f, q = 0.f;
#pragma unroll
    for (int f = 0; f < 8; ++f) { s += acc[f][j]; q += acc[f][j] * acc[f][j]; }
#pragma unroll
    for (int o = 1; o < 16; o <<= 1) {
      s += __shfl_xor(s, o, 64);
      q += __shfl_xor(q, o, 64);
    }
    sum[j] = s; sq[j] = q;
  }
  __syncthreads();                       // all waves done reading Bs
  float* ps = reinterpret_cast<float*>(&Bs[0][0]);        // [4 waves][16 rows]
  float* pq = ps + 64;
  if (l15 == 0) {
#pragma unroll
    for (int j = 0; j < 4; ++j) {
      ps[w * 16 + g * 4 + j] = sum[j];
      pq[w * 16 + g * 4 + j] = sq[j];
    }
  }
  __syncthreads();
#pragma unroll
  for (int j = 0; j < 4; ++j) {
    int row = g * 4 + j;
    float s = ps[row] + ps[16 + row] + ps[32 + row] + ps[48 + row];
    float q = pq[row] + pq[16 + row] + pq[32 + row] + pq[48 + row];
    float mean = s * (1.f / kD);
    float var = q * (1.f / kD) - mean * mean;
    float rs = rsqrtf(var + 1e-5f);
#pragma unroll
    for (int f = 0; f < 8; ++f) {
      int col = w * 128 + f * 16 + l15;
      float y = (acc[f][j] - mean) * rs * gg[f] + tt[f];
      Out[(size_t)(m0 + row) * kD + col] = y;
      if (BF16OUT) OutB[(size_t)(m0 + row) * kD + col] = f2bf(y);
    }
  }
}

// ---------------------------------------------------------------- banded MFMA attention
__global__ __launch_bounds__(256) void attn_mfma(
    const ushort* __restrict__ QK, const ushort* __restrict__ V,
    ushort* __restrict__ Ctx)
{
  constexpr int PAD = 72;
  __shared__ __align__(16) ushort Ks[2][64 * 64];
  __shared__ __align__(16) ushort Vt[2][64][PAD];
  __shared__ __align__(16) ushort Pl[4][16][PAD];
  const int tid = threadIdx.x;
  const int lane = tid & 63, w = tid >> 6;
  const int l15 = lane & 15, g = lane >> 4;
  const int bh = blockIdx.y;
  const int b = bh >> 3, h = bh & 7;
  const int r0 = blockIdx.x * 64;
  const int rowbase = b * kT;
  const int qrow0 = r0 + w * 16;
  const int t_lo = max(r0 - 256, 0);
  const int t_last = min(r0 + 256, kT - 64);
  const int ntiles = ((t_last - t_lo) >> 6) + 1;

  short8 qf[2];
  {
    const size_t qb = (size_t)(rowbase + qrow0 + l15) * 1024 + h * 64 + g * 8;
    qf[0] = *reinterpret_cast<const short8*>(&QK[qb]);
    qf[1] = *reinterpret_cast<const short8*>(&QK[qb + 32]);
  }

  uint4 vreg[2];
  auto issueK = [&](int buf, int j0) {
#pragma unroll
    for (int c = 0; c < 2; ++c) {
      int u = c * 256 + tid;
      int row = u >> 3;
      int col8 = (u & 7) ^ (row & 7);
      const ushort* src =
          &QK[(size_t)(rowbase + j0 + row) * 1024 + 512 + h * 64 + col8 * 8];
      GLOAD_LDS16(src, &Ks[buf][(c * 256 + w * 64) * 8]);
    }
  };
  auto issueV = [&](int j0) {
#pragma unroll
    for (int i = 0; i < 2; ++i)
      vreg[i] = *reinterpret_cast<const uint4*>(
          &V[(size_t)(rowbase + j0 + lane) * 512 + h * 64 + (w + 4 * i) * 8]);
  };
  auto writeV = [&](int buf) {
#pragma unroll
    for (int i = 0; i < 2; ++i) {
      int dg = w + 4 * i;
      ushort tmp[8];
      *reinterpret_cast<uint4*>(tmp) = vreg[i];
#pragma unroll
      for (int e = 0; e < 8; ++e) Vt[buf][dg * 8 + e][lane] = tmp[e];
    }
  };

  f32x4 acc[4];
#pragma unroll
  for (int d = 0; d < 4; ++d) acc[d] = {0.f, 0.f, 0.f, 0.f};
  float mrun[4] = {-1e30f, -1e30f, -1e30f, -1e30f};
  float lrun[4] = {0.f, 0.f, 0.f, 0.f};

  issueK(0, t_lo);
  issueV(t_lo);
  asm volatile("s_waitcnt vmcnt(0)" ::: "memory");
  writeV(0);
  __syncthreads();

  for (int tt = 0; tt < ntiles; ++tt) {
    const int buf = tt & 1;
    const int j0 = t_lo + tt * 64;
    if (tt + 1 < ntiles) {
      issueK(buf ^ 1, j0 + 64);
      issueV(j0 + 64);
    }

    f32x4 s[4];
#pragma unroll
    for (int n = 0; n < 4; ++n) {
      f32x4 z = {0.f, 0.f, 0.f, 0.f};
#pragma unroll
      for (int kc = 0; kc < 2; ++kc) {
        int row = n * 16 + l15;
        int unit = row * 8 + ((kc * 4 + g) ^ (row & 7));
        short8 kb = *reinterpret_cast<const short8*>(&Ks[buf][unit * 8]);
        z = __builtin_amdgcn_mfma_f32_16x16x32_bf16(qf[kc], kb, z, 0, 0, 0);
      }
      s[n] = z;
    }
#pragma unroll
    for (int n = 0; n < 4; ++n)
#pragma unroll
      for (int j = 0; j < 4; ++j) {
        int col = j0 + n * 16 + l15;
        int qr = qrow0 + g * 4 + j;
        int dlt = col - qr;
        float v = s[n][j] * 0.125f;
        s[n][j] = (dlt > 256 || dlt < -256) ? -1e30f : v;
      }
    float pn[4][4];
    float sold[4];
#pragma unroll
    for (int j = 0; j < 4; ++j) {
      float mx = fmaxf(fmaxf(s[0][j], s[1][j]), fmaxf(s[2][j], s[3][j]));
      mx = fmaxf(mx, __shfl_xor(mx, 1));
      mx = fmaxf(mx, __shfl_xor(mx, 2));
      mx = fmaxf(mx, __shfl_xor(mx, 4));
      mx = fmaxf(mx, __shfl_xor(mx, 8));
      float mnew = fmaxf(mrun[j], mx);
      float sc = __expf(mrun[j] - mnew);
      mrun[j] = mnew;
      sold[j] = sc;
      float rs = 0.f;
#pragma unroll
      for (int n = 0; n < 4; ++n) {
        float p = __expf(s[n][j] - mnew);
        pn[n][j] = p;
        rs += p;
      }
      rs += __shfl_xor(rs, 1);
      rs += __shfl_xor(rs, 2);
      rs += __shfl_xor(rs, 4);
      rs += __shfl_xor(rs, 8);
      lrun[j] = lrun[j] * sc + rs;
    }
#pragma unroll
    for (int d = 0; d < 4; ++d)
#pragma unroll
      for (int j = 0; j < 4; ++j) acc[d][j] *= sold[j];
#pragma unroll
    for (int n = 0; n < 4; ++n)
#pragma unroll
      for (int j = 0; j < 4; ++j)
        Pl[w][g * 4 + j][n * 16 + l15] = f2bf(pn[n][j]);
    asm volatile("s_waitcnt lgkmcnt(0)" ::: "memory");
    __builtin_amdgcn_sched_barrier(0);

    short8 pa[2];
    pa[0] = *reinterpret_cast<const short8*>(&Pl[w][l15][g * 8]);
    pa[1] = *reinterpret_cast<const short8*>(&Pl[w][l15][32 + g * 8]);
#pragma unroll
    for (int d = 0; d < 4; ++d) {
#pragma unroll
      for (int kc = 0; kc < 2; ++kc) {
        short8 vb = *reinterpret_cast<const short8*>(
            &Vt[buf][d * 16 + l15][kc * 32 + g * 8]);
        acc[d] = __builtin_amdgcn_mfma_f32_16x16x32_bf16(pa[kc], vb, acc[d], 0, 0, 0);
      }
    }

    if (tt + 1 < ntiles) {
      asm volatile("s_waitcnt vmcnt(0)" ::: "memory");
      writeV(buf ^ 1);
    }
    __syncthreads();
  }

  float inv[4];
#pragma unroll
  for (int j = 0; j < 4; ++j) inv[j] = 1.f / lrun[j];
#pragma unroll
  for (int d = 0; d < 4; ++d)
#pragma unroll
    for (int j = 0; j < 4; ++j) {
      float v = acc[d][j] * inv[j];
      Ctx[(size_t)(rowbase + qrow0 + g * 4 + j) * 512 + h * 64 + d * 16 + l15] =
          f2bf(v);
    }
}

// ---------------------------------------------------------------- launch
extern "C" void kernel_launch(void* const* d_in, const int* in_sizes, int n_in,
                              void* d_out, int out_size, void* d_ws, size_t ws_size,
                              hipStream_t stream)
{
  const float* x   = (const float*)d_in[0];
  const float* cw  = (const float*)d_in[2];
  const float* cb  = (const float*)d_in[3];
  const float* ipw = (const float*)d_in[4];
  const float* ipb = (const float*)d_in[5];
  const float* opw = (const float*)d_in[6];
  const float* opb = (const float*)d_in[7];
  const float* g1  = (const float*)d_in[8];
  const float* b1n = (const float*)d_in[9];
  const float* w1  = (const float*)d_in[10];
  const float* bb1 = (const float*)d_in[11];
  const float* w2  = (const float*)d_in[12];
  const float* bb2 = (const float*)d_in[13];
  const float* g2  = (const float*)d_in[14];
  const float* b2n = (const float*)d_in[15];
  float* out = (float*)d_out;

  char* p = (char*)d_ws;
  auto take = [&](size_t bytes) {
    char* q = p; p += (bytes + 255) & ~size_t(255); return q;
  };
  ushort* xbp   = (ushort*)take((size_t)kB * kTP * kD * 2);
  ushort* wct   = (ushort*)take((size_t)3 * kD * kD * 2);
  ushort* wveff = (ushort*)take((size_t)kD * 3 * kD * 2);
  ushort* ipwb  = (ushort*)take((size_t)3 * kD * kD * 2);
  ushort* opwb  = (ushort*)take((size_t)kD * kD * 2);
  ushort* w1b   = (ushort*)take((size_t)2 * kD * kD * 2);
  ushort* w2b   = (ushort*)take((size_t)2 * kD * kD * 2);
  float* bvpart = (float*)take(4096 * 4);
  float* bveff  = (float*)take(512 * 4);
  char*  qk_r   =          take((size_t)kN * 2 * kD * 2);   // 8MB bf16 q|k
  ushort* qkb   = (ushort*)qk_r;
  ushort* vbb   = (ushort*)take((size_t)kN * kD * 2);
  ushort* ctx   = (ushort*)take((size_t)kN * kD * 2);
  float* hbuf   = (float*)take((size_t)kN * kD * 4);
  ushort* hb    = (ushort*)take((size_t)kN * kD * 2);
  ushort* f1    = (ushort*)qk_r;     // qkb dead after attention

  dim3 blk(256);
  // P0: prep (xbp + weight casts + wct + bias partials)
  prep_kernel<<<dim3(2048), blk, 0, stream>>>(
      x, ipw, opw, w1, w2, cw, cb,
      xbp, ipwb, opwb, w1b, w2b, wct, bvpart);
  // P1: Wv_eff = Wv @ Wc  (+ bveff reduce)
  wprep_kernel<<<dim3(192), blk, 0, stream>>>(
      ipwb, wct, wveff, ipb, bvpart, bveff);
  // P2: q,k,v in one launch (v = strided-view im2col GEMM, K=1536)
  qkv_kernel<<<dim3(1536), blk, 0, stream>>>(
      xbp, ipwb, ipb, wveff, bveff, qkb, vbb);
  // P3: banded MFMA attention -> bf16 ctx
  attn_mfma<<<dim3(kT / 64, kB * 8), blk, 0, stream>>>(qkb, vbb, ctx);
  // P4: h = LN(x + ctx @ Wo^T + bo)  (fused out-proj + residual + LN1)
  gemm_ln<512, 1><<<dim3(kN / 16), blk, 0, stream>>>(
      ctx, opwb, opb, x, g1, b1n, hbuf, hb);
  // P5: ffn1 = relu(h @ w1^T + b1) -> bf16
  gemm_bf16<ushort, 1><<<dim3(kN / 64, 1024 / 64), blk, 0, stream>>>(
      hb, w1b, bb1, f1, 1024, kD);
  // P6: out = LN(h + f1 @ w2^T + b2)  (fused ffn2 + residual + LN2)
  gemm_ln<1024, 0><<<dim3(kN / 16), blk, 0, stream>>>(
      f1, w2b, bb2, hbuf, g2, b2n, out, nullptr);
}

// Round 12
// 198.775 us; speedup vs baseline: 1.1292x; 1.1292x over previous
//
#include <hip/hip_runtime.h>
#include <cstdint>
#include <cstddef>

static constexpr int kT  = 2048;
static constexpr int kD  = 512;
static constexpr int kB  = 2;
static constexpr int kN  = kB * kT;   // 4096 rows

using short8 = __attribute__((ext_vector_type(8))) short;
using f32x4  = __attribute__((ext_vector_type(4))) float;
typedef unsigned short ushort;

__device__ inline ushort f2bf(float f) {
  uint32_t u = __builtin_bit_cast(uint32_t, f);
  uint32_t r = (u + 0x7FFFu + ((u >> 16) & 1u)) >> 16;
  return (ushort)r;
}

#define GLOAD_LDS16(g, l)                                         \
  __builtin_amdgcn_global_load_lds(                               \
      (const __attribute__((address_space(1))) void*)(g),         \
      (__attribute__((address_space(3))) void*)(l), 16, 0, 0)

struct __align__(16) SmemGemm {
  ushort As[2][64 * 128];
  ushort Bs[2][64 * 128];
};                                        // 64 KB

// ---------------------------------------------------------------- fused prep
// casts, conv-weight transpose (wct[ti][c] = cw[c][i][tap]), im2col acat,
// and 8-way partials of Wv@cb for the fused conv+v bias.
__global__ __launch_bounds__(256) void prep_kernel(
    const float* __restrict__ x,   const float* __restrict__ ipw,
    const float* __restrict__ opw, const float* __restrict__ w1,
    const float* __restrict__ w2,  const float* __restrict__ cw,
    const float* __restrict__ cb,
    ushort* __restrict__ xb,   ushort* __restrict__ ipwb,
    ushort* __restrict__ opwb, ushort* __restrict__ w1b,
    ushort* __restrict__ w2b,  ushort* __restrict__ wct,
    ushort* __restrict__ acat, float* __restrict__ bvpart)
{
  constexpr int C0 = 524288;            // xb cast (float4 units)
  constexpr int C1 = C0 + 196608;       // ipw
  constexpr int C2 = C1 + 65536;        // opw
  constexpr int C3 = C2 + 131072;       // w1
  constexpr int C4 = C3 + 131072;       // w2
  constexpr int C5 = C4 + 786432;       // wct (ti,c) units
  constexpr int C6 = C5 + 786432;       // acat (m,tap,i8) units
  constexpr int C7 = C6 + 4096;         // bvpart (o,seg) units

  auto cast4 = [](const float* in, ushort* out, int u) {
    float4 v = *reinterpret_cast<const float4*>(&in[(size_t)u * 4]);
    ushort o[4] = {f2bf(v.x), f2bf(v.y), f2bf(v.z), f2bf(v.w)};
    *reinterpret_cast<uint2*>(&out[(size_t)u * 4]) =
        *reinterpret_cast<uint2*>(o);
  };

  for (int u = blockIdx.x * 256 + threadIdx.x; u < C7; u += gridDim.x * 256) {
    if (u < C0) {
      cast4(x, xb, u);
    } else if (u < C1) {
      cast4(ipw, ipwb, u - C0);
    } else if (u < C2) {
      cast4(opw, opwb, u - C1);
    } else if (u < C3) {
      cast4(w1, w1b, u - C2);
    } else if (u < C4) {
      cast4(w2, w2b, u - C3);
    } else if (u < C5) {
      int t = u - C4;
      int ti = t >> 9, c = t & 511;        // ti = tap*512 + i
      int tap = ti >> 9, i = ti & 511;
      wct[(size_t)ti * 512 + c] = f2bf(cw[((size_t)c * 512 + i) * 3 + tap]);
    } else if (u < C6) {
      int t = u - C5;
      int m = t / 192, r = t - m * 192;
      int tap = r >> 6, i8 = r & 63;
      int tib = (m & (kT - 1)) + tap - 1;
      ushort ob[8] = {0, 0, 0, 0, 0, 0, 0, 0};
      if (tib >= 0 && tib < kT) {
        const float* src = &x[(size_t)(m + tap - 1) * kD + i8 * 8];
        float4 v0 = *reinterpret_cast<const float4*>(src);
        float4 v1 = *reinterpret_cast<const float4*>(src + 4);
        ob[0] = f2bf(v0.x); ob[1] = f2bf(v0.y); ob[2] = f2bf(v0.z);
        ob[3] = f2bf(v0.w); ob[4] = f2bf(v1.x); ob[5] = f2bf(v1.y);
        ob[6] = f2bf(v1.z); ob[7] = f2bf(v1.w);
      }
      *reinterpret_cast<uint4*>(
          &acat[(size_t)m * (3 * kD) + tap * kD + i8 * 8]) =
          *reinterpret_cast<uint4*>(ob);
    } else {
      int t = u - C6;
      int o = t >> 3, seg = t & 7;
      float s = 0.f;
      const float* wr = &ipw[(size_t)(1024 + o) * kD + seg * 64];
      const float* cr = &cb[seg * 64];
#pragma unroll 8
      for (int c = 0; c < 64; ++c) s = fmaf(wr[c], cr[c], s);
      bvpart[t] = s;
    }
  }
}

// ---------------------------------------------------------------- GEMM tile (device)
template <typename OutT, int RELU>
__device__ void gemm_tile(SmemGemm& S,
    const ushort* __restrict__ A, const ushort* __restrict__ W,
    const float* __restrict__ bias, OutT* __restrict__ C,
    int Nn, int K, int m0, int n0)
{
  const int tid = threadIdx.x;
  const int lane = tid & 63, w = tid >> 6;
  const int wr = w >> 1, wc = w & 1;
  const int fr = lane & 15, g = lane >> 4;

  f32x4 acc[2][2];
#pragma unroll
  for (int i = 0; i < 2; ++i)
#pragma unroll
    for (int j = 0; j < 2; ++j) acc[i][j] = {0.f, 0.f, 0.f, 0.f};

  const ushort* gA[4];
  const ushort* gB[4];
#pragma unroll
  for (int i = 0; i < 4; ++i) {
    int u = i * 256 + tid;
    int row = u >> 4, c = (u & 15) ^ (row & 7);
    gA[i] = A + (size_t)(m0 + row) * K + c * 8;
    gB[i] = W + (size_t)(n0 + row) * K + c * 8;
  }

  auto stage = [&](int buf, int k0) {
#pragma unroll
    for (int i = 0; i < 4; ++i)
      GLOAD_LDS16(gA[i] + k0, &S.As[buf][(i * 256 + w * 64) * 8]);
#pragma unroll
    for (int i = 0; i < 4; ++i)
      GLOAD_LDS16(gB[i] + k0, &S.Bs[buf][(i * 256 + w * 64) * 8]);
  };

  const int nt = K >> 7;
  stage(0, 0);
  for (int t = 0; t < nt; ++t) {
    const int buf = t & 1;
    if (t + 1 < nt) {
      stage(buf ^ 1, (t + 1) << 7);
      asm volatile("s_waitcnt vmcnt(8)" ::: "memory");
    } else {
      asm volatile("s_waitcnt vmcnt(0)" ::: "memory");
    }
    __builtin_amdgcn_s_barrier();
    __builtin_amdgcn_sched_barrier(0);

    short8 av[2][4], bv[2][4];
#pragma unroll
    for (int m = 0; m < 2; ++m)
#pragma unroll
      for (int kc = 0; kc < 4; ++kc) {
        int r = wr * 32 + m * 16 + fr;
        av[m][kc] = *reinterpret_cast<const short8*>(
            &S.As[buf][(r * 16 + ((kc * 4 + g) ^ (r & 7))) * 8]);
      }
#pragma unroll
    for (int n = 0; n < 2; ++n)
#pragma unroll
      for (int kc = 0; kc < 4; ++kc) {
        int r = wc * 32 + n * 16 + fr;
        bv[n][kc] = *reinterpret_cast<const short8*>(
            &S.Bs[buf][(r * 16 + ((kc * 4 + g) ^ (r & 7))) * 8]);
      }
#pragma unroll
    for (int m = 0; m < 2; ++m)
#pragma unroll
      for (int n = 0; n < 2; ++n)
#pragma unroll
        for (int kc = 0; kc < 4; ++kc)
          acc[m][n] = __builtin_amdgcn_mfma_f32_16x16x32_bf16(
              av[m][kc], bv[n][kc], acc[m][n], 0, 0, 0);

    __builtin_amdgcn_sched_barrier(0);
    __builtin_amdgcn_s_barrier();
  }

  float bb[2];
#pragma unroll
  for (int n = 0; n < 2; ++n)
    bb[n] = bias ? bias[n0 + wc * 32 + n * 16 + fr] : 0.f;
#pragma unroll
  for (int m = 0; m < 2; ++m) {
#pragma unroll
    for (int j = 0; j < 4; ++j) {
      int row = m0 + wr * 32 + m * 16 + g * 4 + j;
#pragma unroll
      for (int n = 0; n < 2; ++n) {
        int col = n0 + wc * 32 + n * 16 + fr;
        float v = acc[m][n][j] + bb[n];
        if (RELU) v = fmaxf(v, 0.f);
        if constexpr (sizeof(OutT) == 2)
          C[(size_t)row * Nn + col] = (OutT)f2bf(v);
        else
          C[(size_t)row * Nn + col] = (OutT)v;
      }
    }
  }
}

// ---------------------------------------------------------------- GEMM kernels
template <typename OutT, int RELU>
__global__ __launch_bounds__(256) void gemm_bf16(
    const ushort* __restrict__ A, const ushort* __restrict__ W,
    const float* __restrict__ bias, OutT* __restrict__ C, int Nn, int K)
{
  __shared__ SmemGemm S;
  gemm_tile<OutT, RELU>(S, A, W, bias, C, Nn, K,
                        blockIdx.x * 64, blockIdx.y * 64);
}

// Wv_eff = Wv @ Wc (per-tap), plus bveff reduction.
__global__ __launch_bounds__(256) void wprep_kernel(
    const ushort* __restrict__ ipwb, const ushort* __restrict__ wct,
    ushort* __restrict__ wveff, const float* __restrict__ ipb,
    const float* __restrict__ bvpart, float* __restrict__ bveff)
{
  __shared__ SmemGemm S;
  const int bid = blockIdx.x;
  const int m0 = (bid / 24) * 64, n0 = (bid % 24) * 64;
  gemm_tile<ushort, 0>(S, ipwb + (size_t)1024 * kD, wct, nullptr, wveff,
                       3 * kD, kD, m0, n0);
  if (bid < 2) {
    int o = bid * 256 + threadIdx.x;
    float s = ipb[1024 + o];
#pragma unroll
    for (int e = 0; e < 8; ++e) s += bvpart[o * 8 + e];
    bveff[o] = s;
  }
}

// q,k (from xb, K=512) and v (from acat, K=1536, fused conv) in one launch.
__global__ __launch_bounds__(256) void qkv_kernel(
    const ushort* __restrict__ xb, const ushort* __restrict__ acat,
    const ushort* __restrict__ ipwb, const float* __restrict__ ipb,
    const ushort* __restrict__ wveff, const float* __restrict__ bveff,
    ushort* __restrict__ qkb, ushort* __restrict__ vbb)
{
  __shared__ SmemGemm S;
  const int bid = blockIdx.x;
  if (bid < 1024) {
    gemm_tile<ushort, 0>(S, xb, ipwb, ipb, qkb, 1024, kD,
                         (bid >> 4) * 64, (bid & 15) * 64);
  } else {
    const int t = bid - 1024;
    gemm_tile<ushort, 0>(S, acat, wveff, bveff, vbb, kD, 3 * kD,
                         (t >> 3) * 64, (t & 7) * 64);
  }
}

// ---------------------------------------------------------------- banded MFMA attention
// Swapped QK^T: S^T = mfma(K_frag, Q_frag) so each lane owns ONE q-row's
// scores (16 in-register) — softmax is in-lane + 2 shfl_xor (was 32 shfl).
__global__ __launch_bounds__(256) void attn_mfma(
    const ushort* __restrict__ QK, const ushort* __restrict__ V,
    ushort* __restrict__ Ctx)
{
  constexpr int PAD = 72;
  __shared__ __align__(16) ushort Ks[2][64 * 64];
  __shared__ __align__(16) ushort Vt[2][64][PAD];
  __shared__ __align__(16) ushort Pl[4][16][PAD];
  const int tid = threadIdx.x;
  const int lane = tid & 63, w = tid >> 6;
  const int l15 = lane & 15, g = lane >> 4;
  const int bh = blockIdx.y;
  const int b = bh >> 3, h = bh & 7;
  const int r0 = blockIdx.x * 64;
  const int rowbase = b * kT;
  const int qrow0 = r0 + w * 16;
  const int t_lo = max(r0 - 256, 0);
  const int t_last = min(r0 + 256, kT - 64);
  const int ntiles = ((t_last - t_lo) >> 6) + 1;

  short8 qf[2];
  {
    const size_t qb = (size_t)(rowbase + qrow0 + l15) * 1024 + h * 64 + g * 8;
    qf[0] = *reinterpret_cast<const short8*>(&QK[qb]);
    qf[1] = *reinterpret_cast<const short8*>(&QK[qb + 32]);
  }

  uint4 vreg[2];
  auto issueK = [&](int buf, int j0) {
#pragma unroll
    for (int c = 0; c < 2; ++c) {
      int u = c * 256 + tid;
      int row = u >> 3;
      int col8 = (u & 7) ^ (row & 7);
      const ushort* src =
          &QK[(size_t)(rowbase + j0 + row) * 1024 + 512 + h * 64 + col8 * 8];
      GLOAD_LDS16(src, &Ks[buf][(c * 256 + w * 64) * 8]);
    }
  };
  auto issueV = [&](int j0) {
#pragma unroll
    for (int i = 0; i < 2; ++i)
      vreg[i] = *reinterpret_cast<const uint4*>(
          &V[(size_t)(rowbase + j0 + lane) * 512 + h * 64 + (w + 4 * i) * 8]);
  };
  auto writeV = [&](int buf) {
#pragma unroll
    for (int i = 0; i < 2; ++i) {
      int dg = w + 4 * i;
      ushort tmp[8];
      *reinterpret_cast<uint4*>(tmp) = vreg[i];
#pragma unroll
      for (int e = 0; e < 8; ++e) Vt[buf][dg * 8 + e][lane] = tmp[e];
    }
  };

  f32x4 acc[4];
#pragma unroll
  for (int d = 0; d < 4; ++d) acc[d] = {0.f, 0.f, 0.f, 0.f};
  float mrun = -1e30f;    // running max for q-row (qrow0 + l15)
  float lrun = 0.f;       // running denom for q-row (qrow0 + l15)
  const int qglob = qrow0 + l15;

  issueK(0, t_lo);
  issueV(t_lo);
  asm volatile("s_waitcnt vmcnt(0)" ::: "memory");
  writeV(0);
  __syncthreads();

  for (int tt = 0; tt < ntiles; ++tt) {
    const int buf = tt & 1;
    const int j0 = t_lo + tt * 64;
    if (tt + 1 < ntiles) {
      issueK(buf ^ 1, j0 + 64);
      issueV(j0 + 64);
    }

    // S^T = K @ Q^T  (swapped: C row = key = g*4+j within n-block, col = q = l15)
    f32x4 s[4];
#pragma unroll
    for (int n = 0; n < 4; ++n) {
      f32x4 z = {0.f, 0.f, 0.f, 0.f};
#pragma unroll
      for (int kc = 0; kc < 2; ++kc) {
        int row = n * 16 + l15;
        int unit = row * 8 + ((kc * 4 + g) ^ (row & 7));
        short8 kb = *reinterpret_cast<const short8*>(&Ks[buf][unit * 8]);
        z = __builtin_amdgcn_mfma_f32_16x16x32_bf16(kb, qf[kc], z, 0, 0, 0);
      }
      s[n] = z;
    }
    // scale + band mask (key = j0 + n*16 + g*4 + j, q = qglob)
#pragma unroll
    for (int n = 0; n < 4; ++n)
#pragma unroll
      for (int j = 0; j < 4; ++j) {
        int key = j0 + n * 16 + g * 4 + j;
        int dlt = key - qglob;
        float v = s[n][j] * 0.125f;
        s[n][j] = (dlt > 256 || dlt < -256) ? -1e30f : v;
      }
    // in-lane softmax over 16 scores + 2-shfl cross-group reduce
    float mx = -1e30f;
#pragma unroll
    for (int n = 0; n < 4; ++n)
#pragma unroll
      for (int j = 0; j < 4; ++j) mx = fmaxf(mx, s[n][j]);
    mx = fmaxf(mx, __shfl_xor(mx, 16));
    mx = fmaxf(mx, __shfl_xor(mx, 32));
    float mnew = fmaxf(mrun, mx);
    float sc = __expf(mrun - mnew);
    mrun = mnew;
    float rs = 0.f;
    float pn[4][4];
#pragma unroll
    for (int n = 0; n < 4; ++n)
#pragma unroll
      for (int j = 0; j < 4; ++j) {
        float pv = __expf(s[n][j] - mnew);
        pn[n][j] = pv;
        rs += pv;
      }
    rs += __shfl_xor(rs, 16);
    rs += __shfl_xor(rs, 32);
    lrun = lrun * sc + rs;
    // redistribute scale to ctx rows (ctx row = g*4+j; sc lives at lane l15=row)
    float scj[4];
#pragma unroll
    for (int j = 0; j < 4; ++j) scj[j] = __shfl(sc, g * 4 + j, 64);
#pragma unroll
    for (int d = 0; d < 4; ++d)
#pragma unroll
      for (int j = 0; j < 4; ++j) acc[d][j] *= scj[j];
    // P -> bf16 -> per-wave LDS: Pl[w][q=l15][key]
#pragma unroll
    for (int n = 0; n < 4; ++n)
#pragma unroll
      for (int j = 0; j < 4; ++j)
        Pl[w][l15][n * 16 + g * 4 + j] = f2bf(pn[n][j]);
    asm volatile("s_waitcnt lgkmcnt(0)" ::: "memory");
    __builtin_amdgcn_sched_barrier(0);

    short8 pa[2];
    pa[0] = *reinterpret_cast<const short8*>(&Pl[w][l15][g * 8]);
    pa[1] = *reinterpret_cast<const short8*>(&Pl[w][l15][32 + g * 8]);
    // ctx += P @ V
#pragma unroll
    for (int d = 0; d < 4; ++d) {
#pragma unroll
      for (int kc = 0; kc < 2; ++kc) {
        short8 vb = *reinterpret_cast<const short8*>(
            &Vt[buf][d * 16 + l15][kc * 32 + g * 8]);
        acc[d] = __builtin_amdgcn_mfma_f32_16x16x32_bf16(pa[kc], vb, acc[d], 0, 0, 0);
      }
    }

    if (tt + 1 < ntiles) {
      asm volatile("s_waitcnt vmcnt(0)" ::: "memory");
      writeV(buf ^ 1);
    }
    __syncthreads();
  }

  float invl = 1.f / lrun;
  float invj[4];
#pragma unroll
  for (int j = 0; j < 4; ++j) invj[j] = __shfl(invl, g * 4 + j, 64);
#pragma unroll
  for (int d = 0; d < 4; ++d)
#pragma unroll
    for (int j = 0; j < 4; ++j) {
      float v = acc[d][j] * invj[j];
      Ctx[(size_t)(rowbase + qrow0 + g * 4 + j) * 512 + h * 64 + d * 16 + l15] =
          f2bf(v);
    }
}

// ---------------------------------------------------------------- residual + LayerNorm
__global__ __launch_bounds__(256) void ln_kernel(
    const float* __restrict__ A, const float* __restrict__ Bq,
    const float* __restrict__ G, const float* __restrict__ Bt,
    float* __restrict__ Out, ushort* __restrict__ OutB)
{
  const int lane = threadIdx.x & 63;
  const int wv = threadIdx.x >> 6;
  const int row = blockIdx.x * 4 + wv;
  const size_t base = (size_t)row * kD + lane * 8;

  float4 a0 = *reinterpret_cast<const float4*>(&A[base]);
  float4 a1 = *reinterpret_cast<const float4*>(&A[base + 4]);
  float4 b0 = *reinterpret_cast<const float4*>(&Bq[base]);
  float4 b1 = *reinterpret_cast<const float4*>(&Bq[base + 4]);
  float x[8] = {a0.x + b0.x, a0.y + b0.y, a0.z + b0.z, a0.w + b0.w,
                a1.x + b1.x, a1.y + b1.y, a1.z + b1.z, a1.w + b1.w};
  float s = 0.f, ss = 0.f;
#pragma unroll
  for (int i = 0; i < 8; ++i) { s += x[i]; ss += x[i] * x[i]; }
#pragma unroll
  for (int o = 1; o < 64; o <<= 1) {
    s += __shfl_xor(s, o, 64);
    ss += __shfl_xor(ss, o, 64);
  }
  const float mean = s * (1.f / kD);
  const float var = ss * (1.f / kD) - mean * mean;
  const float rs = rsqrtf(var + 1e-5f);

  const int c = lane * 8;
  float4 g0 = *reinterpret_cast<const float4*>(&G[c]);
  float4 g1 = *reinterpret_cast<const float4*>(&G[c + 4]);
  float4 t0 = *reinterpret_cast<const float4*>(&Bt[c]);
  float4 t1 = *reinterpret_cast<const float4*>(&Bt[c + 4]);
  float y[8];
  y[0] = (x[0] - mean) * rs * g0.x + t0.x;
  y[1] = (x[1] - mean) * rs * g0.y + t0.y;
  y[2] = (x[2] - mean) * rs * g0.z + t0.z;
  y[3] = (x[3] - mean) * rs * g0.w + t0.w;
  y[4] = (x[4] - mean) * rs * g1.x + t1.x;
  y[5] = (x[5] - mean) * rs * g1.y + t1.y;
  y[6] = (x[6] - mean) * rs * g1.z + t1.z;
  y[7] = (x[7] - mean) * rs * g1.w + t1.w;
  *reinterpret_cast<float4*>(&Out[base]) = {y[0], y[1], y[2], y[3]};
  *reinterpret_cast<float4*>(&Out[base + 4]) = {y[4], y[5], y[6], y[7]};
  if (OutB) {
    ushort ob[8];
#pragma unroll
    for (int i = 0; i < 8; ++i) ob[i] = f2bf(y[i]);
    *reinterpret_cast<uint4*>(&OutB[base]) = *reinterpret_cast<uint4*>(ob);
  }
}

// ---------------------------------------------------------------- launch
extern "C" void kernel_launch(void* const* d_in, const int* in_sizes, int n_in,
                              void* d_out, int out_size, void* d_ws, size_t ws_size,
                              hipStream_t stream)
{
  const float* x   = (const float*)d_in[0];
  const float* cw  = (const float*)d_in[2];
  const float* cb  = (const float*)d_in[3];
  const float* ipw = (const float*)d_in[4];
  const float* ipb = (const float*)d_in[5];
  const float* opw = (const float*)d_in[6];
  const float* opb = (const float*)d_in[7];
  const float* g1  = (const float*)d_in[8];
  const float* b1n = (const float*)d_in[9];
  const float* w1  = (const float*)d_in[10];
  const float* bb1 = (const float*)d_in[11];
  const float* w2  = (const float*)d_in[12];
  const float* bb2 = (const float*)d_in[13];
  const float* g2  = (const float*)d_in[14];
  const float* b2n = (const float*)d_in[15];
  float* out = (float*)d_out;

  char* p = (char*)d_ws;
  auto take = [&](size_t bytes) {
    char* q = p; p += (bytes + 255) & ~size_t(255); return q;
  };
  ushort* xb    = (ushort*)take((size_t)kN * kD * 2);
  char*  acat_r =          take((size_t)kN * 3 * kD * 2);   // 12MB region
  ushort* acat  = (ushort*)acat_r;
  ushort* wct   = (ushort*)take((size_t)3 * kD * kD * 2);
  ushort* wveff = (ushort*)take((size_t)kD * 3 * kD * 2);
  ushort* ipwb  = (ushort*)take((size_t)3 * kD * kD * 2);
  ushort* opwb  = (ushort*)take((size_t)kD * kD * 2);
  ushort* w1b   = (ushort*)take((size_t)2 * kD * kD * 2);
  ushort* w2b   = (ushort*)take((size_t)2 * kD * kD * 2);
  float* bvpart = (float*)take(4096 * 4);
  float* bveff  = (float*)take(512 * 4);
  char*  qk_r   =          take((size_t)kN * 2 * kD * 2);   // 8MB bf16 q|k
  ushort* qkb   = (ushort*)qk_r;
  ushort* vbb   = (ushort*)take((size_t)kN * kD * 2);
  ushort* ctx   = (ushort*)take((size_t)kN * kD * 2);
  float* hbuf   = (float*)take((size_t)kN * kD * 4);
  ushort* hb    = (ushort*)take((size_t)kN * kD * 2);
  float* attno  = (float*)acat_r;    // acat dead after qkv
  ushort* f1    = (ushort*)qk_r;     // qkb dead after attention
  float* f2     = (float*)acat_r;    // attno dead after LN1

  dim3 blk(256);
  // P0: prep (casts + wct + im2col + bias partials)
  prep_kernel<<<dim3(2048), blk, 0, stream>>>(
      x, ipw, opw, w1, w2, cw, cb,
      xb, ipwb, opwb, w1b, w2b, wct, acat, bvpart);
  // P1: Wv_eff = Wv @ Wc  (+ bveff reduce)
  wprep_kernel<<<dim3(192), blk, 0, stream>>>(
      ipwb, wct, wveff, ipb, bvpart, bveff);
  // P2: q,k,v in one launch (v = fused conv+proj, K=1536)
  qkv_kernel<<<dim3(1536), blk, 0, stream>>>(
      xb, acat, ipwb, ipb, wveff, bveff, qkb, vbb);
  // P3: banded MFMA attention -> bf16 ctx
  attn_mfma<<<dim3(kT / 64, kB * 8), blk, 0, stream>>>(qkb, vbb, ctx);
  // P4: out projection -> fp32
  gemm_bf16<float, 0><<<dim3(kN / 64, kD / 64), blk, 0, stream>>>(
      ctx, opwb, opb, attno, kD, kD);
  // P5: h = LN(x + attn_out)
  ln_kernel<<<dim3(kN / 4), blk, 0, stream>>>(x, attno, g1, b1n, hbuf, hb);
  // P6: ffn1 = relu(h @ w1^T + b1) -> bf16
  gemm_bf16<ushort, 1><<<dim3(kN / 64, 1024 / 64), blk, 0, stream>>>(
      hb, w1b, bb1, f1, 1024, kD);
  // P7: ffn2 -> fp32
  gemm_bf16<float, 0><<<dim3(kN / 64, kD / 64), blk, 0, stream>>>(
      f1, w2b, bb2, f2, kD, 2 * kD);
  // P8: out = LN(h + ffn2)
  ln_kernel<<<dim3(kN / 4), blk, 0, stream>>>(hbuf, f2, g2, b2n, out, nullptr);
}